// Round 1
// baseline (284.244 us; speedup 1.0000x reference)
//
#include <hip/hip_runtime.h>
#include <math.h>

// Problem constants (match reference)
constexpr int NB   = 8;            // batch
constexpr int ND   = 8;            // embedding dim
constexpr int NH   = 512;
constexpr int NW   = 1024;
constexpr int NP   = NH * NW;      // pixels per image = 524288
constexpr int NG   = NP / 4;       // float4 groups per image = 131072
constexpr int NK   = 5;            // instance labels 1..NK
constexpr int BPB  = 128;          // blocks per batch image
constexpr int GPB  = NG / BPB;     // float4 groups per block = 1024
constexpr int NVAL = NK * ND + NK; // 45 reduced values in pass 1

constexpr float DELTA_V = 0.5f;
constexpr float TWO_DELTA_D = 6.0f;   // 2 * DELTA_D
constexpr float GAMMA = 0.001f;

__device__ __forceinline__ float wave_sum(float v) {
#pragma unroll
    for (int off = 32; off > 0; off >>= 1) v += __shfl_down(v, off, 64);
    return v;
}

// ---------------- Pass 1: per-(b,k) embedding sums + counts ----------------
__global__ __launch_bounds__(256) void pass1_kernel(const float* __restrict__ emb,
                                                    const int* __restrict__ mask,
                                                    float* __restrict__ sums,   // [NB][NK][ND]
                                                    float* __restrict__ cnts) { // [NB][NK]
    const int b   = blockIdx.x / BPB;
    const int blk = blockIdx.x % BPB;
    const long base = (long)blk * GPB;

    const float4* emb4 = (const float4*)emb;
    const int4*   m4p  = (const int4*)mask + (long)b * NG;

    float acc[NK][ND];
    float cnt[NK];
#pragma unroll
    for (int k = 0; k < NK; ++k) {
        cnt[k] = 0.f;
#pragma unroll
        for (int d = 0; d < ND; ++d) acc[k][d] = 0.f;
    }

    for (int it = threadIdx.x; it < GPB; it += blockDim.x) {
        const long g = base + it;
        const int4 m = m4p[g];
        float4 e[ND];
#pragma unroll
        for (int d = 0; d < ND; ++d)
            e[d] = emb4[((long)(b * ND + d)) * NG + g];
        const int labs[4] = {m.x, m.y, m.z, m.w};
#pragma unroll
        for (int j = 0; j < 4; ++j) {
            const int lab = labs[j];
#pragma unroll
            for (int k = 0; k < NK; ++k) {
                const float is = (lab == k + 1) ? 1.f : 0.f;
                cnt[k] += is;
#pragma unroll
                for (int d = 0; d < ND; ++d)
                    acc[k][d] = fmaf(is, ((const float*)&e[d])[j], acc[k][d]);
            }
        }
    }

    // block reduction: wave shuffle -> LDS partials -> one atomic per value
    __shared__ float part[4][NVAL];
    const int lane = threadIdx.x & 63;
    const int wave = threadIdx.x >> 6;
#pragma unroll
    for (int k = 0; k < NK; ++k) {
#pragma unroll
        for (int d = 0; d < ND; ++d) {
            const float r = wave_sum(acc[k][d]);
            if (lane == 0) part[wave][k * ND + d] = r;
        }
        const float rc = wave_sum(cnt[k]);
        if (lane == 0) part[wave][NK * ND + k] = rc;
    }
    __syncthreads();
    if (threadIdx.x < NVAL) {
        const float s = part[0][threadIdx.x] + part[1][threadIdx.x] +
                        part[2][threadIdx.x] + part[3][threadIdx.x];
        if (threadIdx.x < NK * ND)
            atomicAdd(&sums[b * NK * ND + threadIdx.x], s);
        else
            atomicAdd(&cnts[b * NK + (threadIdx.x - NK * ND)], s);
    }
}

// ---------------- Pass 2: per-(b,k) variance hinge sums ----------------
__global__ __launch_bounds__(256) void pass2_kernel(const float* __restrict__ emb,
                                                    const int* __restrict__ mask,
                                                    const float* __restrict__ sums,
                                                    const float* __restrict__ cnts,
                                                    float* __restrict__ vsums) { // [NB][NK]
    const int b   = blockIdx.x / BPB;
    const int blk = blockIdx.x % BPB;
    const long base = (long)blk * GPB;

    float c[NK][ND];
#pragma unroll
    for (int k = 0; k < NK; ++k) {
        const float inv = 1.f / fmaxf(cnts[b * NK + k], 1.f);
#pragma unroll
        for (int d = 0; d < ND; ++d)
            c[k][d] = sums[b * NK * ND + k * ND + d] * inv;
    }

    const float4* emb4 = (const float4*)emb;
    const int4*   m4p  = (const int4*)mask + (long)b * NG;

    float vacc[NK] = {0.f, 0.f, 0.f, 0.f, 0.f};

    for (int it = threadIdx.x; it < GPB; it += blockDim.x) {
        const long g = base + it;
        const int4 m = m4p[g];
        float4 e[ND];
#pragma unroll
        for (int d = 0; d < ND; ++d)
            e[d] = emb4[((long)(b * ND + d)) * NG + g];
        const int labs[4] = {m.x, m.y, m.z, m.w};
#pragma unroll
        for (int j = 0; j < 4; ++j) {
            const int lab = labs[j];
            float dsq = 0.f;
#pragma unroll
            for (int d = 0; d < ND; ++d) {
                float cd = c[0][d];
                cd = (lab == 2) ? c[1][d] : cd;
                cd = (lab == 3) ? c[2][d] : cd;
                cd = (lab == 4) ? c[3][d] : cd;
                cd = (lab == 5) ? c[4][d] : cd;
                const float diff = ((const float*)&e[d])[j] - cd;
                dsq = fmaf(diff, diff, dsq);
            }
            const float dist = sqrtf(dsq);
            float hv = fmaxf(dist - DELTA_V, 0.f);
            const float val = hv * hv;
#pragma unroll
            for (int k = 0; k < NK; ++k)
                vacc[k] += (lab == k + 1) ? val : 0.f;
        }
    }

    __shared__ float part[4][NK];
    const int lane = threadIdx.x & 63;
    const int wave = threadIdx.x >> 6;
#pragma unroll
    for (int k = 0; k < NK; ++k) {
        const float r = wave_sum(vacc[k]);
        if (lane == 0) part[wave][k] = r;
    }
    __syncthreads();
    if (threadIdx.x < NK) {
        const float s = part[0][threadIdx.x] + part[1][threadIdx.x] +
                        part[2][threadIdx.x] + part[3][threadIdx.x];
        atomicAdd(&vsums[b * NK + threadIdx.x], s);
    }
}

// ---------------- Final: tiny O(B*K^2) epilogue ----------------
__global__ void final_kernel(const float* __restrict__ sums,
                             const float* __restrict__ cnts,
                             const float* __restrict__ vsums,
                             float* __restrict__ out) {
    if (threadIdx.x != 0 || blockIdx.x != 0) return;
    float tv = 0.f, td = 0.f, tr = 0.f, hs = 0.f;
    for (int b = 0; b < NB; ++b) {
        float cnt[NK];
        bool  pres[NK];
        float c[NK][ND];
        float N = 0.f;
        for (int k = 0; k < NK; ++k) {
            cnt[k]  = cnts[b * NK + k];
            pres[k] = cnt[k] > 0.f;
            if (pres[k]) N += 1.f;
            const float inv = 1.f / fmaxf(cnt[k], 1.f);
            for (int d = 0; d < ND; ++d)
                c[k][d] = sums[b * NK * ND + k * ND + d] * inv;
        }
        // variance loss
        float lv = 0.f;
        for (int k = 0; k < NK; ++k)
            if (pres[k]) lv += vsums[b * NK + k] / fmaxf(cnt[k], 1.f);
        lv /= fmaxf(N, 1.f);
        // distance loss (pairwise i<j)
        float ld = 0.f;
        for (int i = 0; i < NK; ++i)
            for (int j = i + 1; j < NK; ++j)
                if (pres[i] && pres[j]) {
                    float dsq = 0.f;
                    for (int d = 0; d < ND; ++d) {
                        const float df = c[i][d] - c[j][d];
                        dsq = fmaf(df, df, dsq);
                    }
                    const float t = fmaxf(TWO_DELTA_D - sqrtf(dsq), 0.f);
                    ld += t * t;
                }
        const float npairs = N * (N - 1.f) * 0.5f;
        ld /= (N > 1.f) ? npairs : 1.f;
        // regularization
        float lr = 0.f;
        for (int k = 0; k < NK; ++k)
            if (pres[k]) {
                float sq = 0.f;
                for (int d = 0; d < ND; ++d) sq = fmaf(c[k][d], c[k][d], sq);
                lr += sqrtf(sq);
            }
        lr /= fmaxf(N, 1.f);

        if (N > 0.f) { tv += lv; td += ld; tr += lr; hs += 1.f; }
    }
    const float denom = fmaxf(hs, 1.f);
    tv /= denom; td /= denom; tr /= denom;
    out[0] = tv + td + GAMMA * tr;
    out[1] = tv;
    out[2] = td;
    out[3] = tr;
}

extern "C" void kernel_launch(void* const* d_in, const int* in_sizes, int n_in,
                              void* d_out, int out_size, void* d_ws, size_t ws_size,
                              hipStream_t stream) {
    const float* emb  = (const float*)d_in[0];
    const int*   mask = (const int*)d_in[1];
    float* out = (float*)d_out;

    float* sums  = (float*)d_ws;                 // NB*NK*ND = 320
    float* cnts  = sums + NB * NK * ND;          // NB*NK    = 40
    float* vsums = cnts + NB * NK;               // NB*NK    = 40

    hipMemsetAsync(d_ws, 0, (size_t)(NB * NK * ND + 2 * NB * NK) * sizeof(float), stream);

    dim3 grid(NB * BPB), block(256);
    pass1_kernel<<<grid, block, 0, stream>>>(emb, mask, sums, cnts);
    pass2_kernel<<<grid, block, 0, stream>>>(emb, mask, sums, cnts, vsums);
    final_kernel<<<1, 64, 0, stream>>>(sums, cnts, vsums, out);
}